// Round 10
// baseline (9679.018 us; speedup 1.0000x reference)
//
#include <hip/hip_runtime.h>

#define T_STEPS 256
#define B_SZ 256
#define H_SZ 1792
#define IN_SZ 160
#define BH (B_SZ * H_SZ) /* 458752 */
#define NSTEP_REC 56
#define NSTEP_X 5
#define NFRAG_H 112
#define APK_HALF (16 * NSTEP_REC * 2 * 512) /* fp16 elems per A buffer */
#define KS 12 /* k-split ways = waves per block */

typedef __attribute__((ext_vector_type(8))) _Float16 f16x8;
typedef __attribute__((ext_vector_type(4))) _Float16 f16x4;
typedef __attribute__((ext_vector_type(4))) float f32x4;

__device__ __forceinline__ unsigned rotl32(unsigned x, int r) {
  return (x << r) | (x >> (32 - r));
}

__device__ __forceinline__ void threefry2x32(unsigned k0, unsigned k1,
                                             unsigned x0, unsigned x1,
                                             unsigned& o0, unsigned& o1) {
  unsigned ks2 = k0 ^ k1 ^ 0x1BD11BDAu;
  x0 += k0; x1 += k1;
#define TF_R(r) { x0 += x1; x1 = rotl32(x1, (r)); x1 ^= x0; }
  TF_R(13) TF_R(15) TF_R(26) TF_R(6)
  x0 += k1; x1 += ks2 + 1u;
  TF_R(17) TF_R(29) TF_R(16) TF_R(24)
  x0 += ks2; x1 += k0 + 2u;
  TF_R(13) TF_R(15) TF_R(26) TF_R(6)
  x0 += k0; x1 += k1 + 3u;
  TF_R(17) TF_R(29) TF_R(16) TF_R(24)
  x0 += k1; x1 += ks2 + 4u;
  TF_R(13) TF_R(15) TF_R(26) TF_R(6)
  x0 += ks2; x1 += k0 + 5u;
#undef TF_R
  o0 = x0; o1 = x1;
}

__device__ __forceinline__ float erfinv_f32(float x) {
  float w = -log1pf(-x * x);
  float p;
  if (w < 5.0f) {
    w -= 2.5f;
    p = 2.81022636e-08f;
    p = fmaf(p, w, 3.43273939e-07f);
    p = fmaf(p, w, -3.5233877e-06f);
    p = fmaf(p, w, -4.39150654e-06f);
    p = fmaf(p, w, 0.00021858087f);
    p = fmaf(p, w, -0.00125372503f);
    p = fmaf(p, w, -0.00417768164f);
    p = fmaf(p, w, 0.246640727f);
    p = fmaf(p, w, 1.50140941f);
  } else {
    w = sqrtf(w) - 3.0f;
    p = -0.000200214257f;
    p = fmaf(p, w, 0.000100950558f);
    p = fmaf(p, w, 0.00134934322f);
    p = fmaf(p, w, -0.00367342844f);
    p = fmaf(p, w, 0.00573950773f);
    p = fmaf(p, w, -0.0076224613f);
    p = fmaf(p, w, 0.00943887047f);
    p = fmaf(p, w, 1.00167406f);
    p = fmaf(p, w, 2.83297682f);
  }
  return p * x;
}

// JAX partitionable threefry bits = o0 ^ o1 of threefry(key, (0, e)).
__device__ __forceinline__ float jax_normal(unsigned k0, unsigned k1, unsigned e) {
  unsigned o0, o1;
  threefry2x32(k0, k1, 0u, e, o0, o1);
  const unsigned bits = o0 ^ o1;
  float u = __uint_as_float((bits >> 9) | 0x3F800000u) - 1.0f;
  float z = u * 2.0f + (-0.99999994f);
  z = fmaxf(-0.99999994f, z);
  return 1.4142135623730951f * erfinv_f32(z);
}

__global__ void init_keys_kernel(unsigned* __restrict__ keybuf) {
  const unsigned t = threadIdx.x;
  unsigned o0, o1;
  threefry2x32(0u, 42u, 0u, t, o0, o1);
  keybuf[2 * t] = o0;
  keybuf[2 * t + 1] = o1;
}

// fp16 2-way split: w ~= h + m/2048 (m pre-scaled to stay normal).
__device__ __forceinline__ void split2(float w, _Float16& h, _Float16& m) {
  h = (_Float16)w;
  float r = w - (float)h;
  m = (_Float16)(r * 2048.0f);
}

// B_pk[s][f][p][512] : frag elem(lane,j) = B[k=32s+8*(lane>>4)+j][h=16f+(lane&15)]
__global__ void pack_B_kernel(const float* __restrict__ W_in,
                              const float* __restrict__ W_rec,
                              _Float16* __restrict__ Bpk) {
  const int id = blockIdx.x * 256 + threadIdx.x; // 437248
  const int h = id / 244;
  const int ko = id - h * 244;
  const int k0 = ko * 8;
  float w[8];
  if (k0 < H_SZ) {
    const float4* src = reinterpret_cast<const float4*>(&W_rec[(size_t)h * H_SZ + k0]);
    float4 v0 = src[0], v1 = src[1];
    float m;
    if (h < 512)       m = (k0 < 1536) ? 1.0f : 0.0f;
    else if (h < 1536) m = 1.0f;
    else               m = (k0 >= 512) ? 1.0f : 0.0f;
    w[0]=v0.x*m; w[1]=v0.y*m; w[2]=v0.z*m; w[3]=v0.w*m;
    w[4]=v1.x*m; w[5]=v1.y*m; w[6]=v1.z*m; w[7]=v1.w*m;
  } else {
    const int i0 = k0 - H_SZ;
    const float4* src = reinterpret_cast<const float4*>(&W_in[(size_t)h * IN_SZ + i0]);
    float4 v0 = src[0], v1 = src[1];
    float m;
    if (h < 512)       m = (i0 < 128) ? 1.0f : 0.0f;
    else if (h < 1536) m = (i0 >= 128) ? 1.0f : 0.0f;
    else               m = (i0 >= 64 && i0 < 128) ? 1.0f : 0.0f;
    w[0]=v0.x*m; w[1]=v0.y*m; w[2]=v0.z*m; w[3]=v0.w*m;
    w[4]=v1.x*m; w[5]=v1.y*m; w[6]=v1.z*m; w[7]=v1.w*m;
  }
  f16x8 vh, vm;
#pragma unroll
  for (int j = 0; j < 8; ++j) {
    _Float16 a, b;
    split2(w[j], a, b);
    vh[j] = a; vm[j] = b;
  }
  const int s = ko >> 2;
  const int f = h >> 4;
  const int lane = (h & 15) + 16 * (ko & 3);
  _Float16* dst = Bpk + ((size_t)(s * NFRAG_H + f) * 2) * 512 + lane * 8;
  *reinterpret_cast<f16x8*>(dst)       = vh;
  *reinterpret_cast<f16x8*>(dst + 512) = vm;
}

// X_pk[t][bf][sx][p][512] : elem(lane,j) = x[t][b=16bf+(lane&15)][i=32sx+8*(lane>>4)+j]
__global__ void pack_x_kernel(const float* __restrict__ inputs,
                              _Float16* __restrict__ Xpk) {
  const int id = blockIdx.x * 256 + threadIdx.x; // 1310720
  const int io = id % 20;
  const int tb = id / 20;
  const int b = tb & 255;
  const int t = tb >> 8;
  const float4* src = reinterpret_cast<const float4*>(
      &inputs[((size_t)(t * 256 + b)) * IN_SZ + io * 8]);
  float4 v0 = src[0], v1 = src[1];
  float w[8] = {v0.x, v0.y, v0.z, v0.w, v1.x, v1.y, v1.z, v1.w};
  f16x8 vh, vm;
#pragma unroll
  for (int j = 0; j < 8; ++j) {
    _Float16 a, bb;
    split2(w[j], a, bb);
    vh[j] = a; vm[j] = bb;
  }
  const int sx = io >> 2;
  const int lane = (b & 15) + 16 * (io & 3);
  _Float16* dst = Xpk +
      ((size_t)((t * 16 + (b >> 4)) * NSTEP_X + sx) * 2) * 512 + lane * 8;
  *reinterpret_cast<f16x8*>(dst)       = vh;
  *reinterpret_cast<f16x8*>(dst + 512) = vm;
}

__global__ void zero_kernel(float* __restrict__ p, int n) {
  const int i = blockIdx.x * 256 + threadIdx.x;
  if (i < n) p[i] = 0.0f;
}

// grid 224 = 8 bb (32b) x 28 hb (64h); 768 thr = 12 waves (3/SIMD, VGPR cap
// 682 -> no spill). Wave w handles block-list steps i = w, w+12, ...
// Mask-aware step list per h-region skips all-zero W_eff k-blocks:
//   h1 (hb<8):   rec s in [0,48),  X sx in {0,1,2,3} -> n=52
//   h2 (8..23):  rec s in [0,56),  X sx = {4}        -> n=57
//   h3 (24..27): rec s in [16,56), X sx in {2,3}     -> n=42
__global__ __launch_bounds__(768) void eirnn_step(
    const _Float16* __restrict__ Apk_cur,
    _Float16* __restrict__ Apk_next,
    const _Float16* __restrict__ Xpk_t,
    const _Float16* __restrict__ Bpk,
    float* __restrict__ state,
    const float* __restrict__ b_in, const float* __restrict__ b_rec,
    const unsigned* __restrict__ keybuf,
    float* __restrict__ out_t, int t) {
  __shared__ float ldsC[KS][32][68]; // 104 KB -> 1 block/CU

  const int tid = threadIdx.x;
  const int w = tid >> 6;   // 0..11
  const int lane = tid & 63;
  // XCD-chunked swizzle (perf heuristic only).
  const int logical = (blockIdx.x & 7) * 28 + (blockIdx.x >> 3);
  const int hb = logical >> 3; // 0..27
  const int bb = logical & 7;  // 0..7
  const int b0 = bb * 32;

  const int bf0 = b0 >> 4; // 2 A-frags
  const int f0 = hb * 4;   // 4 B-frags
  const int lofs = lane * 8;

  // region step-list parameters (wave-uniform)
  int rec_lo, nrec, xbase, n;
  if (hb < 8)       { rec_lo = 0;  nrec = 48; xbase = 0; n = 52; }
  else if (hb < 24) { rec_lo = 0;  nrec = 56; xbase = 4; n = 57; }
  else              { rec_lo = 16; nrec = 40; xbase = 2; n = 42; }

  f32x4 acc1[2][4] = {};
  f32x4 acc2[2][4] = {};
  f16x8 bA[2][2][2]; // [buf][pi][plane]
  f16x8 bB[2][4][2]; // [buf][qi][plane]

#define LOAD(IB, I)                                                            \
  { const int ii = (I);                                                        \
    if (ii < nrec) {                                                           \
      const int s = rec_lo + ii;                                               \
      _Pragma("unroll")                                                        \
      for (int pi = 0; pi < 2; ++pi) {                                         \
        const _Float16* ap =                                                   \
            Apk_cur + ((size_t)((bf0 + pi) * NSTEP_REC + s) * 2) * 512 + lofs; \
        bA[IB][pi][0] = *reinterpret_cast<const f16x8*>(ap);                   \
        bA[IB][pi][1] = *reinterpret_cast<const f16x8*>(ap + 512);             \
      }                                                                        \
      _Pragma("unroll")                                                        \
      for (int qi = 0; qi < 4; ++qi) {                                         \
        const _Float16* bp =                                                   \
            Bpk + ((size_t)(s * NFRAG_H + f0 + qi) * 2) * 512 + lofs;          \
        bB[IB][qi][0] = *reinterpret_cast<const f16x8*>(bp);                   \
        bB[IB][qi][1] = *reinterpret_cast<const f16x8*>(bp + 512);             \
      }                                                                        \
    } else {                                                                   \
      const int sx = xbase + (ii - nrec);                                      \
      _Pragma("unroll")                                                        \
      for (int pi = 0; pi < 2; ++pi) {                                         \
        const _Float16* ap =                                                   \
            Xpk_t + ((size_t)((bf0 + pi) * NSTEP_X + sx) * 2) * 512 + lofs;    \
        bA[IB][pi][0] = *reinterpret_cast<const f16x8*>(ap);                   \
        bA[IB][pi][1] = *reinterpret_cast<const f16x8*>(ap + 512);             \
      }                                                                        \
      _Pragma("unroll")                                                        \
      for (int qi = 0; qi < 4; ++qi) {                                         \
        const _Float16* bp =                                                   \
            Bpk + ((size_t)((NSTEP_REC + sx) * NFRAG_H + f0 + qi) * 2) * 512 + lofs; \
        bB[IB][qi][0] = *reinterpret_cast<const f16x8*>(bp);                   \
        bB[IB][qi][1] = *reinterpret_cast<const f16x8*>(bp + 512);             \
      }                                                                        \
    } }

#define MM(IB)                                                                 \
  { _Pragma("unroll")                                                          \
    for (int pi = 0; pi < 2; ++pi)                                             \
      _Pragma("unroll")                                                        \
      for (int qi = 0; qi < 4; ++qi) {                                         \
        acc1[pi][qi] = __builtin_amdgcn_mfma_f32_16x16x32_f16(                 \
            bA[IB][pi][0], bB[IB][qi][0], acc1[pi][qi], 0, 0, 0);              \
        acc2[pi][qi] = __builtin_amdgcn_mfma_f32_16x16x32_f16(                 \
            bA[IB][pi][0], bB[IB][qi][1], acc2[pi][qi], 0, 0, 0);              \
        acc2[pi][qi] = __builtin_amdgcn_mfma_f32_16x16x32_f16(                 \
            bA[IB][pi][1], bB[IB][qi][0], acc2[pi][qi], 0, 0, 0);              \
      } }

  // issue first loads before the (VALU-only) noise precompute
  LOAD(0, w)                       // every wave has >= 3 steps (n >= 42 > 11)
  if (w + KS < n) LOAD(1, w + KS)

  // epilogue geometry + noise (threads 0..511; overlaps load latency)
  const int bl = tid >> 4; // 0..31 for tid<512
  const int q  = tid & 15;
  const int h0 = hb * 64 + q * 4;
  const size_t e0 = (size_t)(b0 + (bl & 31)) * H_SZ + h0;
  const float sig = (h0 < 1024 || h0 >= 1536) ? 0.1f : 0.0f;
  float nz[4] = {0.0f, 0.0f, 0.0f, 0.0f};
  if (tid < 512 && sig != 0.0f) {
    const unsigned kk0 = keybuf[2 * t], kk1 = keybuf[2 * t + 1];
#pragma unroll
    for (int j = 0; j < 4; ++j)
      nz[j] = jax_normal(kk0, kk1, (unsigned)(e0 + j));
  }

  // 2-deep pipelined, wave-disjoint k-slices
  for (int i = w; i < n; i += 2 * KS) {
    MM(0)
    if (i + 2 * KS < n) LOAD(0, i + 2 * KS)
    if (i + KS < n) {
      MM(1)
      if (i + 3 * KS < n) LOAD(1, i + 3 * KS)
    }
  }
#undef LOAD
#undef MM

  // scatter partials: row = b-local, col = h-local (validated mapping)
#pragma unroll
  for (int pi = 0; pi < 2; ++pi)
#pragma unroll
    for (int qi = 0; qi < 4; ++qi) {
      const int row = pi * 16 + ((lane >> 4) << 2);
      const int col = qi * 16 + (lane & 15);
#pragma unroll
      for (int r = 0; r < 4; ++r)
        ldsC[w][row + r][col] =
            acc1[pi][qi][r] + acc2[pi][qi][r] * (1.0f / 2048.0f);
    }
  __syncthreads();

  if (tid >= 512) return;

  // ---- reduce KS partials + state update + pack next A (threads 0..511) ----
  f32x4 sum = {0.0f, 0.0f, 0.0f, 0.0f};
#pragma unroll
  for (int ww = 0; ww < KS; ++ww)
    sum += *reinterpret_cast<const f32x4*>(&ldsC[ww][bl][q * 4]);

  const f32x4 sv = *reinterpret_cast<const f32x4*>(&state[e0]);
  const f32x4 bi = *reinterpret_cast<const f32x4*>(&b_in[h0]);
  const f32x4 br = *reinterpret_cast<const f32x4*>(&b_rec[h0]);
  f32x4 so, oo;
  f16x4 vh, vm;
#pragma unroll
  for (int j = 0; j < 4; ++j) {
    float s = sv[j] * 0.6666666865348816f +
              (sum[j] + bi[j] + br[j]) * 0.3333333432674408f;
    s += sig * nz[j];
    const float o = fmaxf(s, 0.0f);
    so[j] = s; oo[j] = o;
    _Float16 xh, xm;
    split2(o, xh, xm);
    vh[j] = xh; vm[j] = xm;
  }
  *reinterpret_cast<f32x4*>(&state[e0]) = so;
  *reinterpret_cast<f32x4*>(&out_t[e0]) = oo;

  const int b = b0 + bl;
  _Float16* dst = Apk_next +
      ((size_t)((b >> 4) * NSTEP_REC + hb * 2 + (q >> 3)) * 2) * 512 +
      ((b & 15) + 16 * ((q >> 1) & 3)) * 8 + (q & 1) * 4;
  *reinterpret_cast<f16x4*>(dst)       = vh;
  *reinterpret_cast<f16x4*>(dst + 512) = vm;
}

__global__ void finalize_kernel(const float* __restrict__ state,
                                const float* __restrict__ last_out,
                                float* __restrict__ dst) {
  const int i = blockIdx.x * 256 + threadIdx.x;
  dst[i] = state[i];
  dst[BH + i] = last_out[i];
}

extern "C" void kernel_launch(void* const* d_in, const int* in_sizes, int n_in,
                              void* d_out, int out_size, void* d_ws, size_t ws_size,
                              hipStream_t stream) {
  const float* inputs = (const float*)d_in[0];
  const float* W_in   = (const float*)d_in[1];
  const float* b_in   = (const float*)d_in[2];
  const float* W_rec  = (const float*)d_in[3];
  const float* b_rec  = (const float*)d_in[4];
  float* out = (float*)d_out;

  char* ws = (char*)d_ws;
  _Float16* Bpk = (_Float16*)ws;                 // 13,991,936 B
  _Float16* Xpk = (_Float16*)(ws + 13991936);    // 41,943,040 B
  _Float16* Apk = (_Float16*)(ws + 55934976);    // 3,670,016 B
  float* state  = (float*)(ws + 59604992);       // 1,835,008 B
  unsigned* keybuf = (unsigned*)(ws + 61440000); // 2,048 B

  init_keys_kernel<<<1, 256, 0, stream>>>(keybuf);
  pack_B_kernel<<<1708, 256, 0, stream>>>(W_in, W_rec, Bpk);
  pack_x_kernel<<<5120, 256, 0, stream>>>(inputs, Xpk);
  zero_kernel<<<1792, 256, 0, stream>>>(state, BH);
  zero_kernel<<<1792, 256, 0, stream>>>((float*)Apk, APK_HALF / 2);

  for (int t = 0; t < T_STEPS; ++t) {
    const int par = t & 1;
    eirnn_step<<<224, 768, 0, stream>>>(
        Apk + (size_t)par * APK_HALF,
        Apk + (size_t)(par ^ 1) * APK_HALF,
        Xpk + (size_t)t * (16 * NSTEP_X * 2 * 512),
        Bpk, state, b_in, b_rec, keybuf, out + (size_t)t * BH, t);
  }

  finalize_kernel<<<1792, 256, 0, stream>>>(
      state, out + (size_t)(T_STEPS - 1) * BH, out + (size_t)T_STEPS * BH);
}

// Round 11
// 3379.869 us; speedup vs baseline: 2.8637x; 2.8637x over previous
//
#include <hip/hip_runtime.h>

#define T_STEPS 256
#define B_SZ 256
#define H_SZ 1792
#define IN_SZ 160
#define BH (B_SZ * H_SZ) /* 458752 */
#define NSTEP_REC 56
#define NSTEP_X 5
#define NFRAG_H 112
#define APK_HALF (16 * NSTEP_REC * 2 * 512) /* fp16 elems per A buffer */
#define KS 8 /* k-split ways = waves per block (512 thr: VGPR cap 256, no spill) */

typedef __attribute__((ext_vector_type(8))) _Float16 f16x8;
typedef __attribute__((ext_vector_type(4))) _Float16 f16x4;
typedef __attribute__((ext_vector_type(4))) float f32x4;

__device__ __forceinline__ unsigned rotl32(unsigned x, int r) {
  return (x << r) | (x >> (32 - r));
}

__device__ __forceinline__ void threefry2x32(unsigned k0, unsigned k1,
                                             unsigned x0, unsigned x1,
                                             unsigned& o0, unsigned& o1) {
  unsigned ks2 = k0 ^ k1 ^ 0x1BD11BDAu;
  x0 += k0; x1 += k1;
#define TF_R(r) { x0 += x1; x1 = rotl32(x1, (r)); x1 ^= x0; }
  TF_R(13) TF_R(15) TF_R(26) TF_R(6)
  x0 += k1; x1 += ks2 + 1u;
  TF_R(17) TF_R(29) TF_R(16) TF_R(24)
  x0 += ks2; x1 += k0 + 2u;
  TF_R(13) TF_R(15) TF_R(26) TF_R(6)
  x0 += k0; x1 += k1 + 3u;
  TF_R(17) TF_R(29) TF_R(16) TF_R(24)
  x0 += k1; x1 += ks2 + 4u;
  TF_R(13) TF_R(15) TF_R(26) TF_R(6)
  x0 += ks2; x1 += k0 + 5u;
#undef TF_R
  o0 = x0; o1 = x1;
}

__device__ __forceinline__ float erfinv_f32(float x) {
  float w = -log1pf(-x * x);
  float p;
  if (w < 5.0f) {
    w -= 2.5f;
    p = 2.81022636e-08f;
    p = fmaf(p, w, 3.43273939e-07f);
    p = fmaf(p, w, -3.5233877e-06f);
    p = fmaf(p, w, -4.39150654e-06f);
    p = fmaf(p, w, 0.00021858087f);
    p = fmaf(p, w, -0.00125372503f);
    p = fmaf(p, w, -0.00417768164f);
    p = fmaf(p, w, 0.246640727f);
    p = fmaf(p, w, 1.50140941f);
  } else {
    w = sqrtf(w) - 3.0f;
    p = -0.000200214257f;
    p = fmaf(p, w, 0.000100950558f);
    p = fmaf(p, w, 0.00134934322f);
    p = fmaf(p, w, -0.00367342844f);
    p = fmaf(p, w, 0.00573950773f);
    p = fmaf(p, w, -0.0076224613f);
    p = fmaf(p, w, 0.00943887047f);
    p = fmaf(p, w, 1.00167406f);
    p = fmaf(p, w, 2.83297682f);
  }
  return p * x;
}

// JAX partitionable threefry bits = o0 ^ o1 of threefry(key, (0, e)).
__device__ __forceinline__ float jax_normal(unsigned k0, unsigned k1, unsigned e) {
  unsigned o0, o1;
  threefry2x32(k0, k1, 0u, e, o0, o1);
  const unsigned bits = o0 ^ o1;
  float u = __uint_as_float((bits >> 9) | 0x3F800000u) - 1.0f;
  float z = u * 2.0f + (-0.99999994f);
  z = fmaxf(-0.99999994f, z);
  return 1.4142135623730951f * erfinv_f32(z);
}

__global__ void init_keys_kernel(unsigned* __restrict__ keybuf) {
  const unsigned t = threadIdx.x;
  unsigned o0, o1;
  threefry2x32(0u, 42u, 0u, t, o0, o1);
  keybuf[2 * t] = o0;
  keybuf[2 * t + 1] = o1;
}

// fp16 2-way split: w ~= h + m/2048 (m pre-scaled to stay normal).
__device__ __forceinline__ void split2(float w, _Float16& h, _Float16& m) {
  h = (_Float16)w;
  float r = w - (float)h;
  m = (_Float16)(r * 2048.0f);
}

// B_pk[s][f][p][512] : frag elem(lane,j) = B[k=32s+8*(lane>>4)+j][h=16f+(lane&15)]
__global__ void pack_B_kernel(const float* __restrict__ W_in,
                              const float* __restrict__ W_rec,
                              _Float16* __restrict__ Bpk) {
  const int id = blockIdx.x * 256 + threadIdx.x; // 437248
  const int h = id / 244;
  const int ko = id - h * 244;
  const int k0 = ko * 8;
  float w[8];
  if (k0 < H_SZ) {
    const float4* src = reinterpret_cast<const float4*>(&W_rec[(size_t)h * H_SZ + k0]);
    float4 v0 = src[0], v1 = src[1];
    float m;
    if (h < 512)       m = (k0 < 1536) ? 1.0f : 0.0f;
    else if (h < 1536) m = 1.0f;
    else               m = (k0 >= 512) ? 1.0f : 0.0f;
    w[0]=v0.x*m; w[1]=v0.y*m; w[2]=v0.z*m; w[3]=v0.w*m;
    w[4]=v1.x*m; w[5]=v1.y*m; w[6]=v1.z*m; w[7]=v1.w*m;
  } else {
    const int i0 = k0 - H_SZ;
    const float4* src = reinterpret_cast<const float4*>(&W_in[(size_t)h * IN_SZ + i0]);
    float4 v0 = src[0], v1 = src[1];
    float m;
    if (h < 512)       m = (i0 < 128) ? 1.0f : 0.0f;
    else if (h < 1536) m = (i0 >= 128) ? 1.0f : 0.0f;
    else               m = (i0 >= 64 && i0 < 128) ? 1.0f : 0.0f;
    w[0]=v0.x*m; w[1]=v0.y*m; w[2]=v0.z*m; w[3]=v0.w*m;
    w[4]=v1.x*m; w[5]=v1.y*m; w[6]=v1.z*m; w[7]=v1.w*m;
  }
  f16x8 vh, vm;
#pragma unroll
  for (int j = 0; j < 8; ++j) {
    _Float16 a, b;
    split2(w[j], a, b);
    vh[j] = a; vm[j] = b;
  }
  const int s = ko >> 2;
  const int f = h >> 4;
  const int lane = (h & 15) + 16 * (ko & 3);
  _Float16* dst = Bpk + ((size_t)(s * NFRAG_H + f) * 2) * 512 + lane * 8;
  *reinterpret_cast<f16x8*>(dst)       = vh;
  *reinterpret_cast<f16x8*>(dst + 512) = vm;
}

// X_pk[t][bf][sx][p][512] : elem(lane,j) = x[t][b=16bf+(lane&15)][i=32sx+8*(lane>>4)+j]
__global__ void pack_x_kernel(const float* __restrict__ inputs,
                              _Float16* __restrict__ Xpk) {
  const int id = blockIdx.x * 256 + threadIdx.x; // 1310720
  const int io = id % 20;
  const int tb = id / 20;
  const int b = tb & 255;
  const int t = tb >> 8;
  const float4* src = reinterpret_cast<const float4*>(
      &inputs[((size_t)(t * 256 + b)) * IN_SZ + io * 8]);
  float4 v0 = src[0], v1 = src[1];
  float w[8] = {v0.x, v0.y, v0.z, v0.w, v1.x, v1.y, v1.z, v1.w};
  f16x8 vh, vm;
#pragma unroll
  for (int j = 0; j < 8; ++j) {
    _Float16 a, bb;
    split2(w[j], a, bb);
    vh[j] = a; vm[j] = bb;
  }
  const int sx = io >> 2;
  const int lane = (b & 15) + 16 * (io & 3);
  _Float16* dst = Xpk +
      ((size_t)((t * 16 + (b >> 4)) * NSTEP_X + sx) * 2) * 512 + lane * 8;
  *reinterpret_cast<f16x8*>(dst)       = vh;
  *reinterpret_cast<f16x8*>(dst + 512) = vm;
}

__global__ void zero_kernel(float* __restrict__ p, int n) {
  const int i = blockIdx.x * 256 + threadIdx.x;
  if (i < n) p[i] = 0.0f;
}

// xin[t] = X_t @ W_in_eff^T + b_in, written into d_out[t*BH ...] (read by the
// step epilogue at step t, then overwritten in-place by out_t).
// grid = T*28: block (t, hb) computes [256b x 64h]; 4 waves, wave w = 4 bf.
__global__ __launch_bounds__(256) void xin_gemm(
    const _Float16* __restrict__ Xpk,
    const _Float16* __restrict__ Bpk,
    const float* __restrict__ b_in,
    float* __restrict__ out) {
  const int tid = threadIdx.x;
  const int w = tid >> 6;
  const int lane = tid & 63;
  const int t = blockIdx.x / 28;
  const int hb = blockIdx.x - t * 28;
  const int bf0 = w * 4;
  const int f0 = hb * 4;
  const int lofs = lane * 8;

  f32x4 acc1[4][4] = {};
  f32x4 acc2[4][4] = {};
#pragma unroll
  for (int s = 0; s < NSTEP_X; ++s) {
    f16x8 a[4][2], b[4][2];
#pragma unroll
    for (int pi = 0; pi < 4; ++pi) {
      const _Float16* ap = Xpk +
          ((size_t)((t * 16 + bf0 + pi) * NSTEP_X + s) * 2) * 512 + lofs;
      a[pi][0] = *reinterpret_cast<const f16x8*>(ap);
      a[pi][1] = *reinterpret_cast<const f16x8*>(ap + 512);
    }
#pragma unroll
    for (int qi = 0; qi < 4; ++qi) {
      const _Float16* bp = Bpk +
          ((size_t)(((NSTEP_REC + s) * NFRAG_H + f0 + qi) * 2)) * 512 + lofs;
      b[qi][0] = *reinterpret_cast<const f16x8*>(bp);
      b[qi][1] = *reinterpret_cast<const f16x8*>(bp + 512);
    }
#pragma unroll
    for (int pi = 0; pi < 4; ++pi)
#pragma unroll
      for (int qi = 0; qi < 4; ++qi) {
        acc1[pi][qi] = __builtin_amdgcn_mfma_f32_16x16x32_f16(
            a[pi][0], b[qi][0], acc1[pi][qi], 0, 0, 0);
        acc2[pi][qi] = __builtin_amdgcn_mfma_f32_16x16x32_f16(
            a[pi][0], b[qi][1], acc2[pi][qi], 0, 0, 0);
        acc2[pi][qi] = __builtin_amdgcn_mfma_f32_16x16x32_f16(
            a[pi][1], b[qi][0], acc2[pi][qi], 0, 0, 0);
      }
  }
  // write: b = (bf0+pi)*16 + (lane>>4)*4 + r; h = hb*64 + qi*16 + (lane&15)
#pragma unroll
  for (int qi = 0; qi < 4; ++qi) {
    const int h = hb * 64 + qi * 16 + (lane & 15);
    const float bi = b_in[h];
#pragma unroll
    for (int pi = 0; pi < 4; ++pi) {
      const int brow = (bf0 + pi) * 16 + ((lane >> 4) << 2);
#pragma unroll
      for (int r = 0; r < 4; ++r) {
        out[(size_t)t * BH + (size_t)(brow + r) * H_SZ + h] =
            acc1[pi][qi][r] + acc2[pi][qi][r] * (1.0f / 2048.0f) + bi;
      }
    }
  }
}

// grid 224 = 8 bb (32b) x 28 hb (64h); 512 thr = 8 waves (2/SIMD, VGPR cap 256
// -> no spill; the ONLY spill-free shape, see R9/R10). Mask-aware rec-only
// k-lists (xin hoisted):
//   h1 (hb<8):   s in [0,48)  n=48
//   h2 (8..23):  s in [0,56)  n=56
//   h3 (24..27): s in [16,56) n=40
__global__ __launch_bounds__(512) void eirnn_step(
    const _Float16* __restrict__ Apk_cur,
    _Float16* __restrict__ Apk_next,
    const _Float16* __restrict__ Bpk,
    float* __restrict__ state,
    const float* __restrict__ b_rec,
    const unsigned* __restrict__ keybuf,
    float* __restrict__ out_t, int t) {
  __shared__ float ldsC[KS][32][68];

  const int tid = threadIdx.x;
  const int w = tid >> 6;   // 0..7
  const int lane = tid & 63;
  // XCD-chunked swizzle (perf heuristic only).
  const int logical = (blockIdx.x & 7) * 28 + (blockIdx.x >> 3);
  const int hb = logical >> 3; // 0..27
  const int bb = logical & 7;  // 0..7
  const int b0 = bb * 32;

  const int bf0 = b0 >> 4; // 2 A-frags
  const int f0 = hb * 4;   // 4 B-frags
  const int lofs = lane * 8;

  // region step-list parameters (wave-uniform)
  int rec_lo, n;
  if (hb < 8)       { rec_lo = 0;  n = 48; }
  else if (hb < 24) { rec_lo = 0;  n = 56; }
  else              { rec_lo = 16; n = 40; }

  f32x4 acc1[2][4] = {};
  f32x4 acc2[2][4] = {};
  f16x8 bA[2][2][2]; // [buf][pi][plane]
  f16x8 bB[2][4][2]; // [buf][qi][plane]

#define LOAD(IB, I)                                                            \
  { const int s = rec_lo + (I);                                                \
    _Pragma("unroll")                                                          \
    for (int pi = 0; pi < 2; ++pi) {                                           \
      const _Float16* ap =                                                     \
          Apk_cur + ((size_t)((bf0 + pi) * NSTEP_REC + s) * 2) * 512 + lofs;   \
      bA[IB][pi][0] = *reinterpret_cast<const f16x8*>(ap);                     \
      bA[IB][pi][1] = *reinterpret_cast<const f16x8*>(ap + 512);               \
    }                                                                          \
    _Pragma("unroll")                                                          \
    for (int qi = 0; qi < 4; ++qi) {                                           \
      const _Float16* bp =                                                     \
          Bpk + ((size_t)(s * NFRAG_H + f0 + qi) * 2) * 512 + lofs;            \
      bB[IB][qi][0] = *reinterpret_cast<const f16x8*>(bp);                     \
      bB[IB][qi][1] = *reinterpret_cast<const f16x8*>(bp + 512);               \
    } }

#define MM(IB)                                                                 \
  { _Pragma("unroll")                                                          \
    for (int pi = 0; pi < 2; ++pi)                                             \
      _Pragma("unroll")                                                        \
      for (int qi = 0; qi < 4; ++qi) {                                         \
        acc1[pi][qi] = __builtin_amdgcn_mfma_f32_16x16x32_f16(                 \
            bA[IB][pi][0], bB[IB][qi][0], acc1[pi][qi], 0, 0, 0);              \
        acc2[pi][qi] = __builtin_amdgcn_mfma_f32_16x16x32_f16(                 \
            bA[IB][pi][0], bB[IB][qi][1], acc2[pi][qi], 0, 0, 0);              \
        acc2[pi][qi] = __builtin_amdgcn_mfma_f32_16x16x32_f16(                 \
            bA[IB][pi][1], bB[IB][qi][0], acc2[pi][qi], 0, 0, 0);              \
      } }

  // issue first loads before the (VALU-only) noise precompute
  LOAD(0, w)                       // every wave has >= 5 steps (n >= 40 > 7)
  if (w + KS < n) LOAD(1, w + KS)

  // epilogue geometry + noise + early state/xin/bias loads
  const int bl = tid >> 4; // 0..31
  const int q  = tid & 15;
  const int h0 = hb * 64 + q * 4;
  const size_t e0 = (size_t)(b0 + bl) * H_SZ + h0;
  const float sig = (h0 < 1024 || h0 >= 1536) ? 0.1f : 0.0f;
  float nz[4] = {0.0f, 0.0f, 0.0f, 0.0f};
  if (sig != 0.0f) {
    const unsigned kk0 = keybuf[2 * t], kk1 = keybuf[2 * t + 1];
#pragma unroll
    for (int j = 0; j < 4; ++j)
      nz[j] = jax_normal(kk0, kk1, (unsigned)(e0 + j));
  }
  const f32x4 xi = *reinterpret_cast<const f32x4*>(&out_t[e0]); // xin(+b_in)
  const f32x4 sv = *reinterpret_cast<const f32x4*>(&state[e0]);
  const f32x4 br = *reinterpret_cast<const f32x4*>(&b_rec[h0]);

  // 2-deep pipelined, wave-disjoint k-slices
  for (int i = w; i < n; i += 2 * KS) {
    MM(0)
    if (i + 2 * KS < n) LOAD(0, i + 2 * KS)
    if (i + KS < n) {
      MM(1)
      if (i + 3 * KS < n) LOAD(1, i + 3 * KS)
    }
  }
#undef LOAD
#undef MM

  // scatter partials: row = b-local, col = h-local (validated mapping)
#pragma unroll
  for (int pi = 0; pi < 2; ++pi)
#pragma unroll
    for (int qi = 0; qi < 4; ++qi) {
      const int row = pi * 16 + ((lane >> 4) << 2);
      const int col = qi * 16 + (lane & 15);
#pragma unroll
      for (int r = 0; r < 4; ++r)
        ldsC[w][row + r][col] =
            acc1[pi][qi][r] + acc2[pi][qi][r] * (1.0f / 2048.0f);
    }
  __syncthreads();

  // ---- reduce KS partials + state update + pack next A ----
  f32x4 sum = {0.0f, 0.0f, 0.0f, 0.0f};
#pragma unroll
  for (int ww = 0; ww < KS; ++ww)
    sum += *reinterpret_cast<const f32x4*>(&ldsC[ww][bl][q * 4]);

  f32x4 so, oo;
  f16x4 vh, vm;
#pragma unroll
  for (int j = 0; j < 4; ++j) {
    float s = sv[j] * 0.6666666865348816f +
              (sum[j] + xi[j] + br[j]) * 0.3333333432674408f;
    s += sig * nz[j];
    const float o = fmaxf(s, 0.0f);
    so[j] = s; oo[j] = o;
    _Float16 xh, xm;
    split2(o, xh, xm);
    vh[j] = xh; vm[j] = xm;
  }
  *reinterpret_cast<f32x4*>(&state[e0]) = so;
  *reinterpret_cast<f32x4*>(&out_t[e0]) = oo;

  const int b = b0 + bl;
  _Float16* dst = Apk_next +
      ((size_t)((b >> 4) * NSTEP_REC + hb * 2 + (q >> 3)) * 2) * 512 +
      ((b & 15) + 16 * ((q >> 1) & 3)) * 8 + (q & 1) * 4;
  *reinterpret_cast<f16x4*>(dst)       = vh;
  *reinterpret_cast<f16x4*>(dst + 512) = vm;
}

__global__ void finalize_kernel(const float* __restrict__ state,
                                const float* __restrict__ last_out,
                                float* __restrict__ dst) {
  const int i = blockIdx.x * 256 + threadIdx.x;
  dst[i] = state[i];
  dst[BH + i] = last_out[i];
}

extern "C" void kernel_launch(void* const* d_in, const int* in_sizes, int n_in,
                              void* d_out, int out_size, void* d_ws, size_t ws_size,
                              hipStream_t stream) {
  const float* inputs = (const float*)d_in[0];
  const float* W_in   = (const float*)d_in[1];
  const float* b_in   = (const float*)d_in[2];
  const float* W_rec  = (const float*)d_in[3];
  const float* b_rec  = (const float*)d_in[4];
  float* out = (float*)d_out;

  char* ws = (char*)d_ws;
  _Float16* Bpk = (_Float16*)ws;                 // 13,991,936 B
  _Float16* Xpk = (_Float16*)(ws + 13991936);    // 41,943,040 B
  _Float16* Apk = (_Float16*)(ws + 55934976);    // 3,670,016 B
  float* state  = (float*)(ws + 59604992);       // 1,835,008 B
  unsigned* keybuf = (unsigned*)(ws + 61440000); // 2,048 B

  init_keys_kernel<<<1, 256, 0, stream>>>(keybuf);
  pack_B_kernel<<<1708, 256, 0, stream>>>(W_in, W_rec, Bpk);
  pack_x_kernel<<<5120, 256, 0, stream>>>(inputs, Xpk);
  zero_kernel<<<1792, 256, 0, stream>>>(state, BH);
  zero_kernel<<<1792, 256, 0, stream>>>((float*)Apk, APK_HALF / 2);

  // xin for all t -> written into d_out (in-place consumed by step epilogues)
  xin_gemm<<<T_STEPS * 28, 256, 0, stream>>>(Xpk, Bpk, b_in, out);

  for (int t = 0; t < T_STEPS; ++t) {
    const int par = t & 1;
    eirnn_step<<<224, 512, 0, stream>>>(
        Apk + (size_t)par * APK_HALF,
        Apk + (size_t)(par ^ 1) * APK_HALF,
        Bpk, state, b_rec, keybuf, out + (size_t)t * BH, t);
  }

  finalize_kernel<<<1792, 256, 0, stream>>>(
      state, out + (size_t)(T_STEPS - 1) * BH, out + (size_t)T_STEPS * BH);
}